// Round 12
// baseline (163.225 us; speedup 1.0000x reference)
//
#include <hip/hip_runtime.h>
#include <hip/hip_bf16.h>

// Problem constants
#define BB 8
#define TT 1024
#define CC 512
#define HH 8
#define EE 256            // head dim (= C/2)
#define MM (BB*TT)        // 8192 rows
#define HE (HH*EE)        // 2048

using short8 = __attribute__((ext_vector_type(8))) short;
using f32x16 = __attribute__((ext_vector_type(16))) float;
using uint2v = __attribute__((ext_vector_type(2))) unsigned int;

__device__ __forceinline__ unsigned short f2bf(float f) {
  union { float f; unsigned int i; } v; v.f = f;
  unsigned int r = v.i + 0x7FFFu + ((v.i >> 16) & 1u);  // RNE
  return (unsigned short)(r >> 16);
}
__device__ __forceinline__ unsigned int pk_bf16(float lo, float hi) {
  unsigned int r;
  asm("v_cvt_pk_bf16_f32 %0, %1, %2" : "=v"(r) : "v"(lo), "v"(hi));
  return r;
}
// async global->LDS, 16B per lane; LDS dest = uniform base + lane*16
__device__ __forceinline__ void gll16(const void* g, void* l) {
  __builtin_amdgcn_global_load_lds(
      (const __attribute__((address_space(1))) unsigned int*)g,
      (__attribute__((address_space(3))) unsigned int*)l, 16, 0, 0);
}

// ---------------------------------------------------------------------------
// Kernel 0: prep — bf16 conversions + fragment-swizzled weights + x1 copy.
//   (unchanged from R9)
// ---------------------------------------------------------------------------
__global__ __launch_bounds__(256) void prep_kernel(const float* __restrict__ x,
                                                   const float* __restrict__ Wq,
                                                   const float* __restrict__ Wk,
                                                   const float* __restrict__ Wv,
                                                   unsigned short* __restrict__ xb,
                                                   unsigned short* __restrict__ wf,
                                                   float* __restrict__ out) {
  int t = blockIdx.x * 256 + threadIdx.x;
  if (t < 262144) {
    int m = t >> 5;
    int c8 = (t & 31) * 8;
    float4 a = *reinterpret_cast<const float4*>(&x[(size_t)m * CC + c8]);
    float4 b = *reinterpret_cast<const float4*>(&x[(size_t)m * CC + c8 + 4]);
    union { unsigned int u[4]; short8 v; } o;
    o.u[0] = pk_bf16(a.x, a.y); o.u[1] = pk_bf16(a.z, a.w);
    o.u[2] = pk_bf16(b.x, b.y); o.u[3] = pk_bf16(b.z, b.w);
    *reinterpret_cast<short8*>(&xb[(size_t)m * 256 + c8]) = o.v;
    *reinterpret_cast<float4*>(&out[(size_t)m * CC + c8]) = a;
    *reinterpret_cast<float4*>(&out[(size_t)m * CC + c8 + 4]) = b;
  } else {
    int t2 = t - 262144;              // [0, 196608)
    int lane = t2 & 63;
    int rest = t2 >> 6;               // [0, 3072)
    int ks = rest & 15;
    int ng = (rest >> 4) & 63;
    int w = rest >> 10;               // 0..2
    const float* Wp = (w == 0) ? Wq : (w == 1) ? Wk : Wv;
    const float scl = (w == 0) ? 0.25f * 1.44269504089f : (w == 1) ? 0.25f : 1.0f;
    int n = ng * 32 + (lane & 31);
    int e0 = ks * 16 + (lane >> 5) * 8;
    float4 a = *reinterpret_cast<const float4*>(&Wp[(size_t)n * EE + e0]);
    float4 b = *reinterpret_cast<const float4*>(&Wp[(size_t)n * EE + e0 + 4]);
    union { unsigned int u[4]; short8 v; } o;
    o.u[0] = pk_bf16(a.x * scl, a.y * scl); o.u[1] = pk_bf16(a.z * scl, a.w * scl);
    o.u[2] = pk_bf16(b.x * scl, b.y * scl); o.u[3] = pk_bf16(b.z * scl, b.w * scl);
    *reinterpret_cast<short8*>(&wf[(size_t)t2 * 8]) = o.v;
  }
}

// ---------------------------------------------------------------------------
// Kernel 1: qkv_static — barrier-free fragment-direct QKV GEMM, BM=128.
//   BM=128, BN=128, K=256 staged ONCE (A-tile [128][256] bf16 = 64KB LDS).
//   256 thr / 4 waves (wc 0..3); per wave acc[3][4] (192 VGPR), 192 MFMAs.
//   Each wf B-fragment load now feeds 4 MFMAs (was 2): block-level wf
//   traffic halved (393 -> 196 MB L2).  Loop has NO barriers.
//   Epilogues: q/k via LDS-vectorized stores; V via LDS transpose.
//   Grid 1024 1-D, mt-inner XCD swizzle.
// ---------------------------------------------------------------------------
__global__ __launch_bounds__(256) void qkv_static_kernel(const unsigned short* __restrict__ xb,
                                                         const unsigned short* __restrict__ wf,
                                                         unsigned short* __restrict__ outq,
                                                         unsigned short* __restrict__ outk,
                                                         unsigned short* __restrict__ outvt) {
  __shared__ unsigned short Ab[128 * 256];     // 64 KB; reused as Tq/Tr in epilogue

  const int tid = threadIdx.x;
  const int lane = tid & 63;
  const int wid = tid >> 6;           // 0..3
  const int wc = wid;                 // n 32-col group
  const int lo = lane & 31, hi = lane >> 5;

  // XCD swizzle: xcd = bid&7 owns mt [xcd*8, xcd*8+8), mt-inner
  int bid = blockIdx.x;
  int r = bid >> 3;                   // [0, 128)
  int mt = (bid & 7) * 8 + (r & 7);   // 0..63
  int nt = r >> 3;                    // 0..15
  const int m0 = mt * 128;
  const int n0 = nt * 128;

  // ---- stage A once: 128 rows x 512 B, wave wid stages rows [32wid,32wid+32)
  {
    const int a_sub = lane >> 5;
    const int a_g = lane & 31;
#pragma unroll
    for (int i = 0; i < 16; ++i) {
      int row = 32 * wid + 2 * i + a_sub;
      int gs = a_g ^ (row & 7);
      gll16(xb + (size_t)(m0 + row) * 256 + gs * 8, Ab + (32 * wid + 2 * i) * 256);
    }
  }
  asm volatile("s_waitcnt vmcnt(0)" ::: "memory");
  __builtin_amdgcn_s_barrier();

  // ---- compute: no barriers in this loop
  f32x16 acc[3][4];
#pragma unroll
  for (int w = 0; w < 3; ++w)
#pragma unroll
    for (int mi = 0; mi < 4; ++mi)
#pragma unroll
      for (int q = 0; q < 16; ++q) acc[w][mi][q] = 0.f;

  const int ng = nt * 4 + wc;
  const short8* wfp = reinterpret_cast<const short8*>(wf);
  const int sxor = lo & 7;

#pragma unroll
  for (int ks = 0; ks < 16; ++ks) {
    short8 bf[3];
#pragma unroll
    for (int w = 0; w < 3; ++w)
      bf[w] = wfp[(size_t)((w * 64 + ng) * 16 + ks) * 64 + lane];
#pragma unroll
    for (int mi = 0; mi < 4; ++mi) {
      int row = 32 * mi + lo;
      int slot = (ks * 2 + hi) ^ sxor;
      short8 af = *reinterpret_cast<const short8*>(&Ab[row * 256 + slot * 8]);
#pragma unroll
      for (int w = 0; w < 3; ++w)
        acc[w][mi] = __builtin_amdgcn_mfma_f32_32x32x16_bf16(af, bf[w], acc[w][mi], 0, 0, 0);
    }
  }

  // ---- epilogue: q, k via LDS store-vectorization ([m][n] tile, pad 136)
  unsigned short* Tq = Ab;            // [128][136] = 34.8 KB <= 64 KB
  const int erow_r = tid >> 4;        // 0..15
  const int en8 = (tid & 15) * 8;     // 0..120
#pragma unroll
  for (int w = 0; w < 2; ++w) {
    unsigned short* op = (w == 0) ? outq : outk;
    __syncthreads();                  // Ab/Tq free (main-loop or prior-w reads done)
#pragma unroll
    for (int mi = 0; mi < 4; ++mi)
#pragma unroll
      for (int q = 0; q < 16; ++q) {
        int rr = (q & 3) + 8 * (q >> 2) + 4 * hi;
        Tq[(32 * mi + rr) * 136 + 32 * wc + lo] = f2bf(acc[w][mi][q]);
      }
    __syncthreads();
#pragma unroll
    for (int p = 0; p < 8; ++p) {
      int row = p * 16 + erow_r;
      *reinterpret_cast<short8*>(&op[(size_t)(m0 + row) * HE + n0 + en8]) =
          *reinterpret_cast<const short8*>(&Tq[row * 136 + en8]);
    }
  }

  // ---- V: LDS transpose (alias A buffer) then coalesced vt stores
  unsigned short* Tr = Ab;            // [128 n][136 m] = 34.8 KB
  __syncthreads();
#pragma unroll
  for (int mi = 0; mi < 4; ++mi)
#pragma unroll
    for (int q = 0; q < 16; ++q) {
      int rr = (q & 3) + 8 * (q >> 2) + 4 * hi;
      Tr[(32 * wc + lo) * 136 + 32 * mi + rr] = f2bf(acc[2][mi][q]);
    }
  __syncthreads();
  {
    const int b = m0 >> 10;
    const int t0m = m0 & 1023;
#pragma unroll
    for (int p = 0; p < 8; ++p) {
      int nr = p * 16 + (tid >> 4);   // 0..127
      int chunk = tid & 15;           // 16 chunks x 8 = 128 m
      int n = n0 + nr;
      size_t drow = ((size_t)b * 8 + (n >> 8)) * 256 + (n & 255);
      *reinterpret_cast<short8*>(&outvt[drow * TT + t0m + chunk * 8]) =
          *reinterpret_cast<const short8*>(&Tr[nr * 136 + chunk * 8]);
    }
  }
}

// ---------------------------------------------------------------------------
// Kernel 2: pipelined MFMA attention (R9-proven structure, byte-identical).
//   256 thr = 4 waves, each wave owns 32 q-rows (QBLK=128), SBLK=32,
//   32 K/V tiles, no s-split.  K[32][256] + Vt[256][32] double-buffered.
//   global_load_lds staging with XOR-granule pre-swizzle on global source.
//   Main loop: stage(t+1, other buf) -> compute(t) -> vmcnt(0)+barrier.
// ---------------------------------------------------------------------------
#define SBLK 32
__global__ __launch_bounds__(256, 2) void attn_kernel(const unsigned short* __restrict__ qg,
                                                      const unsigned short* __restrict__ kg,
                                                      const unsigned short* __restrict__ vtg,
                                                      unsigned short* __restrict__ og) {
  __shared__ char smem[66048];
  unsigned short* Kbuf = (unsigned short*)smem;              // 2 x [32][256]
  unsigned short* Vbuf = (unsigned short*)(smem + 32768);    // 2 x [256][32]
  float* lpart = (float*)(smem + 65536);                     // [128]

  const int tid = threadIdx.x;
  const int lane = tid & 63;
  const int wid = tid >> 6;           // 0..3: q-subtile
  const int lo = lane & 31, hi = lane >> 5;

  // XCD-aware bijective swizzle: 8 t-tiles of each (b,h) stay on one XCD
  int logical = (blockIdx.x & 7) * 64 + (blockIdx.x >> 3);
  const int bh = logical >> 3;
  const int t0 = (logical & 7) * 128;
  const int b = bh >> 3, h = bh & 7;
  const size_t qkbase = (size_t)b * TT * HE + (size_t)h * EE;
  const size_t vtbase = (size_t)bh * EE * TT;
  const unsigned short* kg_base = kg + qkbase;
  const unsigned short* vt_base = vtg + vtbase;

  // hoist Q fragments (B-operand): lane holds q-row t0+32*wid+lo
  short8 qf[16];
  {
    const unsigned short* qrow = qg + qkbase + (size_t)(t0 + 32 * wid + lo) * HE + hi * 8;
#pragma unroll
    for (int ks = 0; ks < 16; ++ks)
      qf[ks] = *reinterpret_cast<const short8*>(qrow + ks * 16);
  }

  f32x16 Oacc[8];
#pragma unroll
  for (int et = 0; et < 8; ++et)
#pragma unroll
    for (int q = 0; q < 16; ++q) Oacc[et][q] = 0.f;
  float lacc = 0.f;

  // staging lane decomposition
  const int k_sub = lane >> 5;        // K: 2 rows / instr
  const int k_g   = lane & 31;
  const int v_er  = lane >> 2;        // V: 16 rows / instr
  const int v_g   = lane & 3;
  const int v_gs  = v_g ^ ((lane >> 3) & 3);

#define STAGE_TILE(TIDX, BUF)                                                        \
  {                                                                                  \
    const unsigned short* kt = kg_base + (size_t)(TIDX) * SBLK * HE;                 \
    const unsigned short* vt = vt_base + (size_t)(TIDX) * SBLK;                      \
    unsigned short* Kb = Kbuf + (BUF) * (SBLK * 256);                                \
    unsigned short* Vb = Vbuf + (BUF) * (256 * SBLK);                                \
    _Pragma("unroll")                                                                \
    for (int i = 0; i < 4; ++i) {                                                    \
      int row = 8 * wid + 2 * i + k_sub;                                             \
      int gs = k_g ^ (row & 7);                                                      \
      gll16(kt + (size_t)row * HE + gs * 8, Kb + (8 * wid + 2 * i) * 256);           \
    }                                                                                \
    _Pragma("unroll")                                                                \
    for (int i = 0; i < 4; ++i) {                                                    \
      int row = 64 * wid + 16 * i + v_er;                                            \
      gll16(vt + (size_t)row * TT + v_gs * 8, Vb + (64 * wid + 16 * i) * SBLK);      \
    }                                                                                \
  }

  STAGE_TILE(0, 0)
  asm volatile("s_waitcnt vmcnt(0)" ::: "memory");
  __builtin_amdgcn_s_barrier();
  __builtin_amdgcn_sched_barrier(0);

  for (int t = 0; t < 32; ++t) {
    const int cur = t & 1;
    if (t + 1 < 32) STAGE_TILE(t + 1, cur ^ 1)

    const unsigned short* Kb = Kbuf + cur * (SBLK * 256);
    const unsigned short* Vb = Vbuf + cur * (256 * SBLK);

    // ---- QK^T (swapped): S^T[32 s x 32 q]
    f32x16 sacc;
#pragma unroll
    for (int q = 0; q < 16; ++q) sacc[q] = 0.f;
    const int sxor = lo & 7;
#pragma unroll
    for (int ks = 0; ks < 16; ++ks) {
      int slot = (ks * 2 + hi) ^ sxor;
      short8 kf = *reinterpret_cast<const short8*>(&Kb[lo * 256 + slot * 8]);
      sacc = __builtin_amdgcn_mfma_f32_32x32x16_bf16(kf, qf[ks], sacc, 0, 0, 0);
    }

    // ---- softmax numerator (exp2; log2e pre-folded) + pack to A-frags
    short8 pa[2];
#pragma unroll
    for (int ksl = 0; ksl < 2; ++ksl) {
      float p0 = __builtin_amdgcn_exp2f(sacc[8 * ksl + 0]);
      float p1 = __builtin_amdgcn_exp2f(sacc[8 * ksl + 1]);
      float p2 = __builtin_amdgcn_exp2f(sacc[8 * ksl + 2]);
      float p3 = __builtin_amdgcn_exp2f(sacc[8 * ksl + 3]);
      float p4 = __builtin_amdgcn_exp2f(sacc[8 * ksl + 4]);
      float p5 = __builtin_amdgcn_exp2f(sacc[8 * ksl + 5]);
      float p6 = __builtin_amdgcn_exp2f(sacc[8 * ksl + 6]);
      float p7 = __builtin_amdgcn_exp2f(sacc[8 * ksl + 7]);
      lacc += ((p0 + p1) + (p2 + p3)) + ((p4 + p5) + (p6 + p7));
      unsigned int a1 = pk_bf16(p0, p1), a2 = pk_bf16(p2, p3);
      unsigned int b1 = pk_bf16(p4, p5), b2 = pk_bf16(p6, p7);
      uint2v r1 = __builtin_amdgcn_permlane32_swap(a1, b1, false, false);
      uint2v r2 = __builtin_amdgcn_permlane32_swap(a2, b2, false, false);
      union { unsigned int u[4]; short8 v; } uu;
      uu.u[0] = r1[0]; uu.u[1] = r2[0]; uu.u[2] = r1[1]; uu.u[3] = r2[1];
      pa[ksl] = uu.v;
    }

    // ---- PV: O[32q][256e] += P[32q][32s] * V[32s][256e]
    const int vxor = (lo >> 1) & 3;
#pragma unroll
    for (int et = 0; et < 8; ++et) {
      const int erow = et * 32 + lo;
#pragma unroll
      for (int ksl = 0; ksl < 2; ++ksl) {
        int slot = (2 * ksl + hi) ^ vxor;
        short8 vf = *reinterpret_cast<const short8*>(&Vb[erow * SBLK + slot * 8]);
        Oacc[et] = __builtin_amdgcn_mfma_f32_32x32x16_bf16(pa[ksl], vf, Oacc[et], 0, 0, 0);
      }
    }

    asm volatile("s_waitcnt vmcnt(0)" ::: "memory");
    __builtin_amdgcn_s_barrier();
    __builtin_amdgcn_sched_barrier(0);
  }

  // ---- epilogue: fold hi halves of lacc, redistribute by q-row, store
  lacc += __shfl_xor(lacc, 32);
  if (hi == 0) lpart[wid * 32 + lo] = lacc;
  __syncthreads();
#pragma unroll
  for (int q = 0; q < 16; ++q) {
    int rr = (q & 3) + 8 * (q >> 2) + 4 * hi;
    float inv = 1.0f / lpart[wid * 32 + rr];
    int tq = t0 + 32 * wid + rr;
#pragma unroll
    for (int et = 0; et < 8; ++et)
      og[qkbase + (size_t)tq * HE + et * 32 + lo] = f2bf(Oacc[et][q] * inv);
  }
#undef STAGE_TILE
}

// ---------------------------------------------------------------------------
// Kernel 3: output projection (MFMA) + bias + residual (unchanged from R9).
// ---------------------------------------------------------------------------
#define PSTR 72
__global__ __launch_bounds__(256) void proj_mfma_kernel(const unsigned short* __restrict__ ao,
                                                        const float* __restrict__ Wu,
                                                        const float* __restrict__ bu,
                                                        const float* __restrict__ x,
                                                        float* __restrict__ out) {
  __shared__ unsigned short As[64 * PSTR];
  __shared__ unsigned short Bs[64 * PSTR];
  const int tid = threadIdx.x;
  const int lane = tid & 63;
  const int wid = tid >> 6;
  const int wr = wid >> 1, wc = wid & 1;
  const int lo = lane & 31, hi = lane >> 5;

  int bid = blockIdx.x;
  int r = bid >> 3;
  int mt = (bid & 7) * 16 + (r & 15);   // 0..127
  int nt = r >> 4;                      // 0..3
  const int m0 = mt * 64;
  const int n0 = nt * 64;

  const int arow = tid >> 2;            // 0..63
  const int ag0 = (tid & 3) * 2;        // bf16 granule pair {ag0, ag0+1} of 8
  const int brow = tid >> 2;            // 0..63
  const int bg0 = (tid & 3) * 4;        // float4 index base (4 per thread of 16)

  short8 raA[2];
  float4 raB[4];
  f32x16 acc;
#pragma unroll
  for (int q = 0; q < 16; ++q) acc[q] = 0.f;

#pragma unroll
  for (int j = 0; j < 2; ++j)
    raA[j] = *reinterpret_cast<const short8*>(&ao[(size_t)(m0 + arow) * HE + (ag0 + j) * 8]);
#pragma unroll
  for (int g = 0; g < 4; ++g)
    raB[g] = *reinterpret_cast<const float4*>(&Wu[(size_t)(n0 + brow) * HE + (bg0 + g) * 4]);

  for (int t = 0; t < 32; ++t) {
#pragma unroll
    for (int j = 0; j < 2; ++j)
      *reinterpret_cast<short8*>(&As[arow * PSTR + (ag0 + j) * 8]) = raA[j];
    {
      union { unsigned int u[4]; short8 v; } w0, w1;
      w0.u[0] = pk_bf16(raB[0].x, raB[0].y); w0.u[1] = pk_bf16(raB[0].z, raB[0].w);
      w0.u[2] = pk_bf16(raB[1].x, raB[1].y); w0.u[3] = pk_bf16(raB[1].z, raB[1].w);
      w1.u[0] = pk_bf16(raB[2].x, raB[2].y); w1.u[1] = pk_bf16(raB[2].z, raB[2].w);
      w1.u[2] = pk_bf16(raB[3].x, raB[3].y); w1.u[3] = pk_bf16(raB[3].z, raB[3].w);
      *reinterpret_cast<short8*>(&Bs[brow * PSTR + ag0 * 8]) = w0.v;
      *reinterpret_cast<short8*>(&Bs[brow * PSTR + (ag0 + 1) * 8]) = w1.v;
    }
    asm volatile("s_waitcnt lgkmcnt(0)" ::: "memory");
    __builtin_amdgcn_s_barrier();
    __builtin_amdgcn_sched_barrier(0);

    if (t + 1 < 32) {
      int k0 = (t + 1) * 64;
#pragma unroll
      for (int j = 0; j < 2; ++j)
        raA[j] = *reinterpret_cast<const short8*>(&ao[(size_t)(m0 + arow) * HE + k0 + (ag0 + j) * 8]);
#pragma unroll
      for (int g = 0; g < 4; ++g)
        raB[g] = *reinterpret_cast<const float4*>(&Wu[(size_t)(n0 + brow) * HE + k0 + (bg0 + g) * 4]);
    }

    __builtin_amdgcn_s_setprio(1);
#pragma unroll
    for (int ks = 0; ks < 4; ++ks) {
      short8 af = *reinterpret_cast<const short8*>(&As[(32 * wr + lo) * PSTR + ks * 16 + hi * 8]);
      short8 bf = *reinterpret_cast<const short8*>(&Bs[(32 * wc + lo) * PSTR + ks * 16 + hi * 8]);
      acc = __builtin_amdgcn_mfma_f32_32x32x16_bf16(af, bf, acc, 0, 0, 0);
    }
    __builtin_amdgcn_s_setprio(0);
    __builtin_amdgcn_s_barrier();
    __builtin_amdgcn_sched_barrier(0);
  }

  {
    int n = n0 + 32 * wc + lo;
    float bias = bu[n];
#pragma unroll
    for (int q = 0; q < 16; ++q) {
      int rr = (q & 3) + 8 * (q >> 2) + 4 * hi;
      int m = m0 + 32 * wr + rr;
      float o = acc[q] + x[(size_t)m * CC + EE + n] + bias;
      out[(size_t)m * CC + EE + n] = o;
    }
  }
}

// ---------------------------------------------------------------------------
extern "C" void kernel_launch(void* const* d_in, const int* in_sizes, int n_in,
                              void* d_out, int out_size, void* d_ws, size_t ws_size,
                              hipStream_t stream) {
  const float* x  = (const float*)d_in[0];
  const float* Wq = (const float*)d_in[1];
  const float* Wk = (const float*)d_in[2];
  const float* Wv = (const float*)d_in[3];
  const float* Wu = (const float*)d_in[4];
  const float* bu = (const float*)d_in[5];
  float* out = (float*)d_out;

  // ws layout (128 MB): q | k | vt | ao (xb+wf alias ao, dead after qkv)
  unsigned short* q  = (unsigned short*)d_ws;
  unsigned short* k  = q + (size_t)MM * HE;
  unsigned short* vt = k + (size_t)MM * HE;
  unsigned short* ao = vt + (size_t)MM * HE;
  unsigned short* xb = ao;                       // [8192][256] bf16 (4 MB)
  unsigned short* wfb = xb + (size_t)MM * EE;    // frag weights (3 MB)

  prep_kernel<<<dim3(1792), dim3(256), 0, stream>>>(x, Wq, Wk, Wv, xb, wfb, out);

  qkv_static_kernel<<<dim3(1024), dim3(256), 0, stream>>>(xb, wfb, q, k, vt);

  attn_kernel<<<dim3(512), dim3(256), 0, stream>>>(q, k, vt, ao);

  proj_mfma_kernel<<<dim3(512), dim3(256), 0, stream>>>(ao, Wu, bu, x, out);
}

// Round 13
// 141.633 us; speedup vs baseline: 1.1524x; 1.1524x over previous
//
#include <hip/hip_runtime.h>
#include <hip/hip_bf16.h>

// Problem constants
#define BB 8
#define TT 1024
#define CC 512
#define HH 8
#define EE 256            // head dim (= C/2)
#define MM (BB*TT)        // 8192 rows
#define HE (HH*EE)        // 2048

using short8 = __attribute__((ext_vector_type(8))) short;
using f32x16 = __attribute__((ext_vector_type(16))) float;
using uint2v = __attribute__((ext_vector_type(2))) unsigned int;

__device__ __forceinline__ unsigned short f2bf(float f) {
  union { float f; unsigned int i; } v; v.f = f;
  unsigned int r = v.i + 0x7FFFu + ((v.i >> 16) & 1u);  // RNE
  return (unsigned short)(r >> 16);
}
__device__ __forceinline__ unsigned int pk_bf16(float lo, float hi) {
  unsigned int r;
  asm("v_cvt_pk_bf16_f32 %0, %1, %2" : "=v"(r) : "v"(lo), "v"(hi));
  return r;
}
// async global->LDS, 16B per lane; LDS dest = uniform base + lane*16
__device__ __forceinline__ void gll16(const void* g, void* l) {
  __builtin_amdgcn_global_load_lds(
      (const __attribute__((address_space(1))) unsigned int*)g,
      (__attribute__((address_space(3))) unsigned int*)l, 16, 0, 0);
}

// ---------------------------------------------------------------------------
// Fragment layouts in workspace (one 16B slot = 8 bf16, index = slot*8):
//   K frag:  kfrag[(((bh*32 + stile)*16 + ks)*64 + lane)]
//            lane=(lo,hi): k[t = stile*32+lo][e = ks*16 + hi*8 + j]
//   V frag:  vfrag[((((bh*32 + stile)*8 + et)*2 + ksl)*64 + lane)]
//            lane=(lo,hi): v[s = stile*32 + ksl*16 + hi*8 + j][e = et*32+lo]
// Attn then stages tiles LINEARLY (16KB, gll16 both-sides-linear) and every
// compute ds_read_b128 is lane-consecutive => conflict-free.
// ---------------------------------------------------------------------------

// ---------------------------------------------------------------------------
// Kernel 0: prep — bf16 conversions + fragment-swizzled weights + x1 copy.
//   (unchanged from R9)
// ---------------------------------------------------------------------------
__global__ __launch_bounds__(256) void prep_kernel(const float* __restrict__ x,
                                                   const float* __restrict__ Wq,
                                                   const float* __restrict__ Wk,
                                                   const float* __restrict__ Wv,
                                                   unsigned short* __restrict__ xb,
                                                   unsigned short* __restrict__ wf,
                                                   float* __restrict__ out) {
  int t = blockIdx.x * 256 + threadIdx.x;
  if (t < 262144) {
    int m = t >> 5;
    int c8 = (t & 31) * 8;
    float4 a = *reinterpret_cast<const float4*>(&x[(size_t)m * CC + c8]);
    float4 b = *reinterpret_cast<const float4*>(&x[(size_t)m * CC + c8 + 4]);
    union { unsigned int u[4]; short8 v; } o;
    o.u[0] = pk_bf16(a.x, a.y); o.u[1] = pk_bf16(a.z, a.w);
    o.u[2] = pk_bf16(b.x, b.y); o.u[3] = pk_bf16(b.z, b.w);
    *reinterpret_cast<short8*>(&xb[(size_t)m * 256 + c8]) = o.v;
    *reinterpret_cast<float4*>(&out[(size_t)m * CC + c8]) = a;
    *reinterpret_cast<float4*>(&out[(size_t)m * CC + c8 + 4]) = b;
  } else {
    int t2 = t - 262144;              // [0, 196608)
    int lane = t2 & 63;
    int rest = t2 >> 6;               // [0, 3072)
    int ks = rest & 15;
    int ng = (rest >> 4) & 63;
    int w = rest >> 10;               // 0..2
    const float* Wp = (w == 0) ? Wq : (w == 1) ? Wk : Wv;
    const float scl = (w == 0) ? 0.25f * 1.44269504089f : (w == 1) ? 0.25f : 1.0f;
    int n = ng * 32 + (lane & 31);
    int e0 = ks * 16 + (lane >> 5) * 8;
    float4 a = *reinterpret_cast<const float4*>(&Wp[(size_t)n * EE + e0]);
    float4 b = *reinterpret_cast<const float4*>(&Wp[(size_t)n * EE + e0 + 4]);
    union { unsigned int u[4]; short8 v; } o;
    o.u[0] = pk_bf16(a.x * scl, a.y * scl); o.u[1] = pk_bf16(a.z * scl, a.w * scl);
    o.u[2] = pk_bf16(b.x * scl, b.y * scl); o.u[3] = pk_bf16(b.z * scl, b.w * scl);
    *reinterpret_cast<short8*>(&wf[(size_t)t2 * 8]) = o.v;
  }
}

// ---------------------------------------------------------------------------
// Kernel 1: qkv_static — barrier-free fragment-direct QKV GEMM (BM=64, R11).
//   NEW epilogues: k and V are written to FRAGMENT-MAJOR workspace layouts
//   (via the existing LDS transpose tiles, same instruction counts).
// ---------------------------------------------------------------------------
__global__ __launch_bounds__(256) void qkv_static_kernel(const unsigned short* __restrict__ xb,
                                                         const unsigned short* __restrict__ wf,
                                                         unsigned short* __restrict__ outq,
                                                         unsigned short* __restrict__ kfrag,
                                                         unsigned short* __restrict__ vfrag) {
  __shared__ unsigned short Ab[64 * 256];      // 32 KB; reused as Tq/Tr in epilogue

  const int tid = threadIdx.x;
  const int lane = tid & 63;
  const int wid = tid >> 6;           // 0..3
  const int wc = wid;                 // n 32-col group
  const int lo = lane & 31, hi = lane >> 5;

  int bid = blockIdx.x;
  int r = bid >> 3;                   // [0, 256)
  int mt = (bid & 7) * 16 + (r & 15); // 0..127
  int nt = r >> 4;                    // 0..15
  const int m0 = mt * 64;
  const int n0 = nt * 128;

  // ---- stage A once
  {
    const int a_sub = lane >> 5;
    const int a_g = lane & 31;
#pragma unroll
    for (int i = 0; i < 8; ++i) {
      int row = 16 * wid + 2 * i + a_sub;
      int gs = a_g ^ (row & 7);
      gll16(xb + (size_t)(m0 + row) * 256 + gs * 8, Ab + (16 * wid + 2 * i) * 256);
    }
  }
  asm volatile("s_waitcnt vmcnt(0)" ::: "memory");
  __builtin_amdgcn_s_barrier();

  f32x16 acc[3][2];
#pragma unroll
  for (int w = 0; w < 3; ++w)
#pragma unroll
    for (int mi = 0; mi < 2; ++mi)
#pragma unroll
      for (int q = 0; q < 16; ++q) acc[w][mi][q] = 0.f;

  const int ng = nt * 4 + wc;
  const short8* wfp = reinterpret_cast<const short8*>(wf);
  const int sxor = lo & 7;

#pragma unroll
  for (int ks = 0; ks < 16; ++ks) {
    short8 bf[3];
#pragma unroll
    for (int w = 0; w < 3; ++w)
      bf[w] = wfp[(size_t)((w * 64 + ng) * 16 + ks) * 64 + lane];
    short8 af[2];
#pragma unroll
    for (int mi = 0; mi < 2; ++mi) {
      int row = 32 * mi + lo;
      int slot = (ks * 2 + hi) ^ sxor;
      af[mi] = *reinterpret_cast<const short8*>(&Ab[row * 256 + slot * 8]);
    }
#pragma unroll
    for (int w = 0; w < 3; ++w)
#pragma unroll
      for (int mi = 0; mi < 2; ++mi)
        acc[w][mi] = __builtin_amdgcn_mfma_f32_32x32x16_bf16(af[mi], bf[w], acc[w][mi], 0, 0, 0);
  }

  const int bh = (m0 >> 10) * 8 + (n0 >> 8);
  const int stile0 = (m0 & 1023) >> 5;   // two stiles: stile0, stile0+1

  // ---- q epilogue: LDS tile + linear coalesced [m][n] stores (R11 path)
  unsigned short* Tq = Ab;            // [64][140]
  {
    __syncthreads();                  // main-loop Ab reads done
#pragma unroll
    for (int mi = 0; mi < 2; ++mi)
#pragma unroll
      for (int q = 0; q < 16; ++q) {
        int rr = (q & 3) + 8 * (q >> 2) + 4 * hi;
        Tq[(32 * mi + rr) * 140 + 32 * wc + lo] = f2bf(acc[0][mi][q]);
      }
    __syncthreads();
    const int erow_r = tid >> 4;
    const int en8 = (tid & 15) * 8;
#pragma unroll
    for (int p = 0; p < 4; ++p) {
      int row = p * 16 + erow_r;
      *reinterpret_cast<short8*>(&outq[(size_t)(m0 + row) * HE + n0 + en8]) =
          *reinterpret_cast<const short8*>(&Tq[row * 140 + en8]);
    }
  }

  // ---- k epilogue: LDS tile + FRAGMENT-major stores
  {
    __syncthreads();
#pragma unroll
    for (int mi = 0; mi < 2; ++mi)
#pragma unroll
      for (int q = 0; q < 16; ++q) {
        int rr = (q & 3) + 8 * (q >> 2) + 4 * hi;
        Tq[(32 * mi + rr) * 140 + 32 * wc + lo] = f2bf(acc[1][mi][q]);
      }
    __syncthreads();
#pragma unroll
    for (int j = 0; j < 4; ++j) {
      int slot = j * 256 + tid;
      int l64 = slot & 63, lo64 = l64 & 31, hi64 = l64 >> 5;
      int rest = slot >> 6;           // 0..15
      int ksl_ = rest & 7, stl = rest >> 3;
      short8 vv = *reinterpret_cast<const short8*>(
          &Tq[(stl * 32 + lo64) * 140 + ksl_ * 16 + hi64 * 8]);
      int ks_g = ((n0 & 255) >> 4) + ksl_;
      size_t dst = (((size_t)(bh * 32 + stile0 + stl) * 16 + ks_g) * 64 + l64) * 8;
      *reinterpret_cast<short8*>(&kfrag[dst]) = vv;
    }
  }

  // ---- V epilogue: LDS transpose + FRAGMENT-major stores
  unsigned short* Tr = Ab;            // [128 n][72 t]
  {
    __syncthreads();
#pragma unroll
    for (int mi = 0; mi < 2; ++mi)
#pragma unroll
      for (int q = 0; q < 16; ++q) {
        int rr = (q & 3) + 8 * (q >> 2) + 4 * hi;
        Tr[(32 * wc + lo) * 72 + 32 * mi + rr] = f2bf(acc[2][mi][q]);
      }
    __syncthreads();
#pragma unroll
    for (int j = 0; j < 4; ++j) {
      int slot = j * 256 + tid;
      int l64 = slot & 63, lo64 = l64 & 31, hi64 = l64 >> 5;
      int rest = slot >> 6;           // 0..15
      int et_l = rest & 3, ksl = (rest >> 2) & 1, stl = rest >> 3;
      short8 vv = *reinterpret_cast<const short8*>(
          &Tr[(et_l * 32 + lo64) * 72 + stl * 32 + ksl * 16 + hi64 * 8]);
      int et_g = ((n0 & 255) >> 5) + et_l;
      size_t dst = ((((size_t)(bh * 32 + stile0 + stl) * 8 + et_g) * 2 + ksl) * 64 + l64) * 8;
      *reinterpret_cast<short8*>(&vfrag[dst]) = vv;
    }
  }
}

// ---------------------------------------------------------------------------
// Kernel 2: pipelined MFMA attention, fragment-major K/V.
//   Same R9 schedule (stage(t+1) -> compute(t) -> vmcnt(0)+barrier, 2 blk/CU),
//   but staging is both-sides-linear (no swizzle) and every compute
//   ds_read_b128 is lane-consecutive (conflict-free).
// ---------------------------------------------------------------------------
#define TILE_EL 8192   // 16 KB per K or V tile (32 s x 256 e bf16)
__global__ __launch_bounds__(256, 2) void attn_kernel(const unsigned short* __restrict__ qg,
                                                      const unsigned short* __restrict__ kfrag,
                                                      const unsigned short* __restrict__ vfrag,
                                                      unsigned short* __restrict__ og) {
  __shared__ char smem[66048];
  unsigned short* Kbuf = (unsigned short*)smem;              // 2 x 8192 elems
  unsigned short* Vbuf = (unsigned short*)(smem + 32768);    // 2 x 8192 elems
  float* lpart = (float*)(smem + 65536);                     // [128]

  const int tid = threadIdx.x;
  const int lane = tid & 63;
  const int wid = tid >> 6;           // 0..3: q-subtile
  const int lo = lane & 31, hi = lane >> 5;
  const int l8 = lane * 8;

  // XCD-aware bijective swizzle: 8 t-tiles of each (b,h) stay on one XCD
  int logical = (blockIdx.x & 7) * 64 + (blockIdx.x >> 3);
  const int bh = logical >> 3;
  const int t0 = (logical & 7) * 128;
  const int b = bh >> 3, h = bh & 7;
  const size_t qkbase = (size_t)b * TT * HE + (size_t)h * EE;
  const unsigned short* kf_base = kfrag + (size_t)bh * 32 * TILE_EL;
  const unsigned short* vf_base = vfrag + (size_t)bh * 32 * TILE_EL;

  // hoist Q fragments (B-operand): lane holds q-row t0+32*wid+lo
  short8 qf[16];
  {
    const unsigned short* qrow = qg + qkbase + (size_t)(t0 + 32 * wid + lo) * HE + hi * 8;
#pragma unroll
    for (int ks = 0; ks < 16; ++ks)
      qf[ks] = *reinterpret_cast<const short8*>(qrow + ks * 16);
  }

  f32x16 Oacc[8];
#pragma unroll
  for (int et = 0; et < 8; ++et)
#pragma unroll
    for (int q = 0; q < 16; ++q) Oacc[et][q] = 0.f;
  float lacc = 0.f;

  // linear staging: tile = 16 chunks of 1KB; wave wid stages chunks [4wid,4wid+4)
#define STAGE_TILE(TIDX, BUF)                                                        \
  {                                                                                  \
    const unsigned short* kt = kf_base + (size_t)(TIDX) * TILE_EL;                   \
    const unsigned short* vt = vf_base + (size_t)(TIDX) * TILE_EL;                   \
    unsigned short* Kb = Kbuf + (BUF) * TILE_EL;                                     \
    unsigned short* Vb = Vbuf + (BUF) * TILE_EL;                                     \
    _Pragma("unroll")                                                                \
    for (int i = 0; i < 4; ++i) {                                                    \
      int c = 4 * wid + i;                                                           \
      gll16(kt + c * 512 + l8, Kb + c * 512);                                        \
      gll16(vt + c * 512 + l8, Vb + c * 512);                                        \
    }                                                                                \
  }

  STAGE_TILE(0, 0)
  asm volatile("s_waitcnt vmcnt(0)" ::: "memory");
  __builtin_amdgcn_s_barrier();
  __builtin_amdgcn_sched_barrier(0);

  for (int t = 0; t < 32; ++t) {
    const int cur = t & 1;
    if (t + 1 < 32) STAGE_TILE(t + 1, cur ^ 1)

    const unsigned short* Kb = Kbuf + cur * TILE_EL;
    const unsigned short* Vb = Vbuf + cur * TILE_EL;

    // ---- QK^T (swapped): S^T[32 s x 32 q]; conflict-free frag reads
    f32x16 sacc;
#pragma unroll
    for (int q = 0; q < 16; ++q) sacc[q] = 0.f;
#pragma unroll
    for (int ks = 0; ks < 16; ++ks) {
      short8 kf = *reinterpret_cast<const short8*>(&Kb[ks * 512 + l8]);
      sacc = __builtin_amdgcn_mfma_f32_32x32x16_bf16(kf, qf[ks], sacc, 0, 0, 0);
    }

    // ---- softmax numerator (exp2; log2e pre-folded) + pack to A-frags
    short8 pa[2];
#pragma unroll
    for (int ksl = 0; ksl < 2; ++ksl) {
      float p0 = __builtin_amdgcn_exp2f(sacc[8 * ksl + 0]);
      float p1 = __builtin_amdgcn_exp2f(sacc[8 * ksl + 1]);
      float p2 = __builtin_amdgcn_exp2f(sacc[8 * ksl + 2]);
      float p3 = __builtin_amdgcn_exp2f(sacc[8 * ksl + 3]);
      float p4 = __builtin_amdgcn_exp2f(sacc[8 * ksl + 4]);
      float p5 = __builtin_amdgcn_exp2f(sacc[8 * ksl + 5]);
      float p6 = __builtin_amdgcn_exp2f(sacc[8 * ksl + 6]);
      float p7 = __builtin_amdgcn_exp2f(sacc[8 * ksl + 7]);
      lacc += ((p0 + p1) + (p2 + p3)) + ((p4 + p5) + (p6 + p7));
      unsigned int a1 = pk_bf16(p0, p1), a2 = pk_bf16(p2, p3);
      unsigned int b1 = pk_bf16(p4, p5), b2 = pk_bf16(p6, p7);
      uint2v r1 = __builtin_amdgcn_permlane32_swap(a1, b1, false, false);
      uint2v r2 = __builtin_amdgcn_permlane32_swap(a2, b2, false, false);
      union { unsigned int u[4]; short8 v; } uu;
      uu.u[0] = r1[0]; uu.u[1] = r2[0]; uu.u[2] = r1[1]; uu.u[3] = r2[1];
      pa[ksl] = uu.v;
    }

    // ---- PV: conflict-free frag reads
#pragma unroll
    for (int et = 0; et < 8; ++et) {
#pragma unroll
      for (int ksl = 0; ksl < 2; ++ksl) {
        short8 vf = *reinterpret_cast<const short8*>(&Vb[(et * 2 + ksl) * 512 + l8]);
        Oacc[et] = __builtin_amdgcn_mfma_f32_32x32x16_bf16(pa[ksl], vf, Oacc[et], 0, 0, 0);
      }
    }

    asm volatile("s_waitcnt vmcnt(0)" ::: "memory");
    __builtin_amdgcn_s_barrier();
    __builtin_amdgcn_sched_barrier(0);
  }

  // ---- epilogue: fold hi halves of lacc, redistribute by q-row, store
  lacc += __shfl_xor(lacc, 32);
  if (hi == 0) lpart[wid * 32 + lo] = lacc;
  __syncthreads();
#pragma unroll
  for (int q = 0; q < 16; ++q) {
    int rr = (q & 3) + 8 * (q >> 2) + 4 * hi;
    float inv = 1.0f / lpart[wid * 32 + rr];
    int tq = t0 + 32 * wid + rr;
#pragma unroll
    for (int et = 0; et < 8; ++et)
      og[qkbase + (size_t)tq * HE + et * 32 + lo] = f2bf(Oacc[et][q] * inv);
  }
#undef STAGE_TILE
}

// ---------------------------------------------------------------------------
// Kernel 3: output projection (MFMA) + bias + residual (unchanged).
// ---------------------------------------------------------------------------
#define PSTR 72
__global__ __launch_bounds__(256) void proj_mfma_kernel(const unsigned short* __restrict__ ao,
                                                        const float* __restrict__ Wu,
                                                        const float* __restrict__ bu,
                                                        const float* __restrict__ x,
                                                        float* __restrict__ out) {
  __shared__ unsigned short As[64 * PSTR];
  __shared__ unsigned short Bs[64 * PSTR];
  const int tid = threadIdx.x;
  const int lane = tid & 63;
  const int wid = tid >> 6;
  const int wr = wid >> 1, wc = wid & 1;
  const int lo = lane & 31, hi = lane >> 5;

  int bid = blockIdx.x;
  int r = bid >> 3;
  int mt = (bid & 7) * 16 + (r & 15);   // 0..127
  int nt = r >> 4;                      // 0..3
  const int m0 = mt * 64;
  const int n0 = nt * 64;

  const int arow = tid >> 2;            // 0..63
  const int ag0 = (tid & 3) * 2;        // bf16 granule pair {ag0, ag0+1} of 8
  const int brow = tid >> 2;            // 0..63
  const int bg0 = (tid & 3) * 4;        // float4 index base (4 per thread of 16)

  short8 raA[2];
  float4 raB[4];
  f32x16 acc;
#pragma unroll
  for (int q = 0; q < 16; ++q) acc[q] = 0.f;

#pragma unroll
  for (int j = 0; j < 2; ++j)
    raA[j] = *reinterpret_cast<const short8*>(&ao[(size_t)(m0 + arow) * HE + (ag0 + j) * 8]);
#pragma unroll
  for (int g = 0; g < 4; ++g)
    raB[g] = *reinterpret_cast<const float4*>(&Wu[(size_t)(n0 + brow) * HE + (bg0 + g) * 4]);

  for (int t = 0; t < 32; ++t) {
#pragma unroll
    for (int j = 0; j < 2; ++j)
      *reinterpret_cast<short8*>(&As[arow * PSTR + (ag0 + j) * 8]) = raA[j];
    {
      union { unsigned int u[4]; short8 v; } w0, w1;
      w0.u[0] = pk_bf16(raB[0].x, raB[0].y); w0.u[1] = pk_bf16(raB[0].z, raB[0].w);
      w0.u[2] = pk_bf16(raB[1].x, raB[1].y); w0.u[3] = pk_bf16(raB[1].z, raB[1].w);
      w1.u[0] = pk_bf16(raB[2].x, raB[2].y); w1.u[1] = pk_bf16(raB[2].z, raB[2].w);
      w1.u[2] = pk_bf16(raB[3].x, raB[3].y); w1.u[3] = pk_bf16(raB[3].z, raB[3].w);
      *reinterpret_cast<short8*>(&Bs[brow * PSTR + ag0 * 8]) = w0.v;
      *reinterpret_cast<short8*>(&Bs[brow * PSTR + (ag0 + 1) * 8]) = w1.v;
    }
    asm volatile("s_waitcnt lgkmcnt(0)" ::: "memory");
    __builtin_amdgcn_s_barrier();
    __builtin_amdgcn_sched_barrier(0);

    if (t + 1 < 32) {
      int k0 = (t + 1) * 64;
#pragma unroll
      for (int j = 0; j < 2; ++j)
        raA[j] = *reinterpret_cast<const short8*>(&ao[(size_t)(m0 + arow) * HE + k0 + (ag0 + j) * 8]);
#pragma unroll
      for (int g = 0; g < 4; ++g)
        raB[g] = *reinterpret_cast<const float4*>(&Wu[(size_t)(n0 + brow) * HE + k0 + (bg0 + g) * 4]);
    }

    __builtin_amdgcn_s_setprio(1);
#pragma unroll
    for (int ks = 0; ks < 4; ++ks) {
      short8 af = *reinterpret_cast<const short8*>(&As[(32 * wr + lo) * PSTR + ks * 16 + hi * 8]);
      short8 bf = *reinterpret_cast<const short8*>(&Bs[(32 * wc + lo) * PSTR + ks * 16 + hi * 8]);
      acc = __builtin_amdgcn_mfma_f32_32x32x16_bf16(af, bf, acc, 0, 0, 0);
    }
    __builtin_amdgcn_s_setprio(0);
    __builtin_amdgcn_s_barrier();
    __builtin_amdgcn_sched_barrier(0);
  }

  {
    int n = n0 + 32 * wc + lo;
    float bias = bu[n];
#pragma unroll
    for (int q = 0; q < 16; ++q) {
      int rr = (q & 3) + 8 * (q >> 2) + 4 * hi;
      int m = m0 + 32 * wr + rr;
      float o = acc[q] + x[(size_t)m * CC + EE + n] + bias;
      out[(size_t)m * CC + EE + n] = o;
    }
  }
}

// ---------------------------------------------------------------------------
extern "C" void kernel_launch(void* const* d_in, const int* in_sizes, int n_in,
                              void* d_out, int out_size, void* d_ws, size_t ws_size,
                              hipStream_t stream) {
  const float* x  = (const float*)d_in[0];
  const float* Wq = (const float*)d_in[1];
  const float* Wk = (const float*)d_in[2];
  const float* Wv = (const float*)d_in[3];
  const float* Wu = (const float*)d_in[4];
  const float* bu = (const float*)d_in[5];
  float* out = (float*)d_out;

  // ws layout (128 MB): q | kfrag | vfrag | ao (xb+wf alias ao, dead after qkv)
  unsigned short* q     = (unsigned short*)d_ws;
  unsigned short* kfrag = q + (size_t)MM * HE;
  unsigned short* vfrag = kfrag + (size_t)MM * HE;
  unsigned short* ao    = vfrag + (size_t)MM * HE;
  unsigned short* xb    = ao;                     // [8192][256] bf16 (4 MB)
  unsigned short* wfb   = xb + (size_t)MM * EE;   // frag weights (3 MB)

  prep_kernel<<<dim3(1792), dim3(256), 0, stream>>>(x, Wq, Wk, Wv, xb, wfb, out);

  qkv_static_kernel<<<dim3(2048), dim3(256), 0, stream>>>(xb, wfb, q, kfrag, vfrag);

  attn_kernel<<<dim3(512), dim3(256), 0, stream>>>(q, kfrag, vfrag, ao);

  proj_mfma_kernel<<<dim3(512), dim3(256), 0, stream>>>(ao, Wu, bu, x, out);
}